// Round 3
// baseline (154.496 us; speedup 1.0000x reference)
//
#include <hip/hip_runtime.h>

#define PNUM 128
#define BATCH 8192
#define NPAIR (2 * BATCH)        // 16384 (batch, pred) pairs
#define WAVES_PER_BLOCK 4        // 1 wave (64 lanes) per pair
#define GRID1 (NPAIR / WAVES_PER_BLOCK)

// Branchless smooth-L1: m = min(|d|,1):  0.5*m*m + (|d| - m)
__device__ __forceinline__ float sl1(float d) {
    float a = fabsf(d);
    float m = fminf(a, 1.0f);
    return fmaf(0.5f * m, m, a - m);
}

// One WAVE per (batch,pred) pair. Lane k owns shifts {2k, 2k+1}.
// gt ring staged doubled in LDS (per-wave region -> no barrier needed);
// sliding float4 window: one consecutive-block ds_read_b128 per 2 j
// (4 terms) = 4 B/term LDS traffic, structurally conflict-free.
// pred read straight from global (same addr across wave -> 1 L1 line).
__global__ __launch_bounds__(64 * WAVES_PER_BLOCK) void match_stage1(
        const float* __restrict__ pred0,
        const float* __restrict__ pred1,
        const float* __restrict__ gt,
        float* __restrict__ ws) {
    __shared__ float2 sg[WAVES_PER_BLOCK][2 * PNUM];   // doubled ring, 2KB/wave

    const int t = threadIdx.x;
    const int k = t & 63;                 // lane
    const int w = t >> 6;                 // wave in block
    const int pr = blockIdx.x * WAVES_PER_BLOCK + w;
    const int b  = pr >> 1;
    const float* predsel = (pr & 1) ? pred1 : pred0;

    // ---- stage gt -> LDS doubled (this wave's region only; no __syncthreads) ----
    const float4* gv4 = (const float4*)(gt + (size_t)b * (PNUM * 2));
    float4* sg4 = (float4*)sg[w];
    float4 gA = gv4[k];
    sg4[k]      = gA;
    sg4[k + 64] = gA;

    const float4* gw4 = (const float4*)sg[w];                 // 128 float4
    const float4* pp4 = (const float4*)(predsel + (size_t)b * (PNUM * 2));

    // init window: ring[2k], ring[2k+1]
    float4 w01 = gw4[k];
    float a0 = 0.f, a1 = 0.f;

#pragma unroll 8
    for (int h = 0; h < PNUM / 2; ++h) {        // h = j/2, j = 2h
        float4 n01 = gw4[k + h + 1];            // ring[2k+j+2], ring[2k+j+3]
        float4 p01 = pp4[h];                    // p[j], p[j+1] (wave-uniform addr)

        // shift 2k   : (p[j], ring[2k+j])   + (p[j+1], ring[2k+j+1])
        a0 += sl1(p01.x - w01.x) + sl1(p01.y - w01.y);
        a0 += sl1(p01.z - w01.z) + sl1(p01.w - w01.w);
        // shift 2k+1 : (p[j], ring[2k+j+1]) + (p[j+1], ring[2k+j+2])
        a1 += sl1(p01.x - w01.z) + sl1(p01.y - w01.w);
        a1 += sl1(p01.z - n01.x) + sl1(p01.w - n01.y);

        w01 = n01;
    }

    // min over this lane's 2 shifts, then over the 64-lane wave
    float r = fminf(a0, a1);
#pragma unroll
    for (int m = 32; m > 0; m >>= 1)
        r = fminf(r, __shfl_xor(r, m, 64));
    if (k == 0) ws[pr] = r;
}

// Sum 16384 per-pair mins -> scalar. 1024 threads, 16 independent loads each.
__global__ __launch_bounds__(1024) void match_stage2(
        const float* __restrict__ ws, float* __restrict__ out) {
    const int t = threadIdx.x;
    float s = 0.f;
#pragma unroll
    for (int q = 0; q < NPAIR / 1024; ++q) s += ws[t + q * 1024];
#pragma unroll
    for (int m = 32; m > 0; m >>= 1) s += __shfl_xor(s, m, 64);

    __shared__ float wsum[16];
    if ((t & 63) == 0) wsum[t >> 6] = s;
    __syncthreads();
    if (t == 0) {
        float tot = 0.f;
#pragma unroll
        for (int i = 0; i < 16; ++i) tot += wsum[i];
        // mean over j (1/PNUM), mean over batch (1/BATCH), avg of two preds (1/2)
        out[0] = tot * (1.0f / (2.0f * BATCH * PNUM));
    }
}

extern "C" void kernel_launch(void* const* d_in, const int* in_sizes, int n_in,
                              void* d_out, int out_size, void* d_ws, size_t ws_size,
                              hipStream_t stream) {
    const float* pred0 = (const float*)d_in[0];
    const float* pred1 = (const float*)d_in[1];
    const float* gt    = (const float*)d_in[2];
    float* out = (float*)d_out;
    float* ws  = (float*)d_ws;   // NPAIR floats = 64 KiB

    match_stage1<<<GRID1, 64 * WAVES_PER_BLOCK, 0, stream>>>(pred0, pred1, gt, ws);
    match_stage2<<<1, 1024, 0, stream>>>(ws, out);
}

// Round 4
// 128.837 us; speedup vs baseline: 1.1992x; 1.1992x over previous
//
#include <hip/hip_runtime.h>

#define PNUM 128
#define BATCH 8192
#define NPAIR (2 * BATCH)
#define WPB 4                    // waves (batches) per block
#define GRID1 (BATCH / WPB)      // 2048 blocks of 256 threads

// smooth-L1 accumulate, 4 VALU: sl1(d) = m*(|d| - 0.5m), m = min(|d|,1)
//   a<1: m=a -> a*(a-0.5a) = 0.5a^2 ;  a>=1: m=1 -> a-0.5
__device__ __forceinline__ float term(float p, float q, float acc) {
    float d = p - q;                       // v_sub
    float m = fminf(fabsf(d), 1.0f);       // v_min (|d| via src modifier)
    float t = fmaf(-0.5f, m, fabsf(d));    // v_fma: |d| - 0.5m
    return fmaf(m, t, acc);                // v_fma: acc += m*t
}

// One WAVE per batch, handling BOTH preds (shared gt ring).
// Lane k owns shifts {2k, 2k+1}. gt ring doubled in per-wave LDS;
// sliding float4 window = 1 ds_read_b128 per 2 j (contiguous lanes).
// pred rows read via wave-uniform (readfirstlane-forced) scalar loads.
__global__ __launch_bounds__(64 * WPB) void match_stage1(
        const float* __restrict__ pred0,
        const float* __restrict__ pred1,
        const float* __restrict__ gt,
        float* __restrict__ ws) {
    __shared__ float4 sg4[WPB][2 * PNUM / 2];   // doubled ring, 2 KB/wave

    const int t = threadIdx.x;
    const int k = t & 63;
    const int w = __builtin_amdgcn_readfirstlane(t >> 6);   // wave-uniform
    const int b = blockIdx.x * WPB + w;                     // uniform batch id

    // ---- stage gt -> LDS doubled (own region only; no barrier needed) ----
    const float4* gv4 = (const float4*)(gt + (size_t)b * (PNUM * 2));
    float4 gA = gv4[k];
    sg4[w][k]      = gA;
    sg4[w][k + 64] = gA;

    const float4* gw4 = sg4[w];                               // 128 float4
    const float4* p0v = (const float4*)(pred0 + (size_t)b * (PNUM * 2));
    const float4* p1v = (const float4*)(pred1 + (size_t)b * (PNUM * 2));

    float4 w01 = gw4[k];            // {ring[2k], ring[2k+1]}
    float4 P0 = p0v[0], P1 = p1v[0];

    // accumulators: [shift 2k | 2k+1] x [pred0 | pred1]
    float a0p0 = 0.f, a1p0 = 0.f, a0p1 = 0.f, a1p1 = 0.f;

#pragma unroll 8
    for (int h = 0; h < PNUM / 2; ++h) {
        float4 n01 = gw4[k + h + 1];            // {ring[2k+2h+2], ring[2k+2h+3]}
        int hn = (h + 1) & 63;                  // uniform; wraps to stay in-bounds
        float4 P0n = p0v[hn];
        float4 P1n = p1v[hn];

        // shift 2k : p[2h] vs w01.xy, p[2h+1] vs w01.zw
        a0p0 = term(P0.x, w01.x, a0p0); a0p0 = term(P0.y, w01.y, a0p0);
        a0p0 = term(P0.z, w01.z, a0p0); a0p0 = term(P0.w, w01.w, a0p0);
        a0p1 = term(P1.x, w01.x, a0p1); a0p1 = term(P1.y, w01.y, a0p1);
        a0p1 = term(P1.z, w01.z, a0p1); a0p1 = term(P1.w, w01.w, a0p1);
        // shift 2k+1 : p[2h] vs w01.zw, p[2h+1] vs n01.xy
        a1p0 = term(P0.x, w01.z, a1p0); a1p0 = term(P0.y, w01.w, a1p0);
        a1p0 = term(P0.z, n01.x, a1p0); a1p0 = term(P0.w, n01.y, a1p0);
        a1p1 = term(P1.x, w01.z, a1p1); a1p1 = term(P1.y, w01.w, a1p1);
        a1p1 = term(P1.z, n01.x, a1p1); a1p1 = term(P1.w, n01.y, a1p1);

        w01 = n01; P0 = P0n; P1 = P1n;
    }

    // min over this lane's 2 shifts (per pred), then over the wave
    float r0 = fminf(a0p0, a1p0);
    float r1 = fminf(a0p1, a1p1);
#pragma unroll
    for (int m = 32; m > 0; m >>= 1) {
        r0 = fminf(r0, __shfl_xor(r0, m, 64));
        r1 = fminf(r1, __shfl_xor(r1, m, 64));
    }
    if (k == 0) {
        ws[2 * b]     = r0;
        ws[2 * b + 1] = r1;
    }
}

// Sum 16384 per-pair mins -> scalar. float4 loads, 4 independent per thread.
__global__ __launch_bounds__(1024) void match_stage2(
        const float* __restrict__ ws, float* __restrict__ out) {
    const int t = threadIdx.x;
    const float4* ws4 = (const float4*)ws;      // 4096 float4
    float s = 0.f;
#pragma unroll
    for (int q = 0; q < 4; ++q) {
        float4 v = ws4[t + q * 1024];
        s += (v.x + v.y) + (v.z + v.w);
    }
#pragma unroll
    for (int m = 32; m > 0; m >>= 1) s += __shfl_xor(s, m, 64);

    __shared__ float wsum[16];
    if ((t & 63) == 0) wsum[t >> 6] = s;
    __syncthreads();
    if (t == 0) {
        float tot = 0.f;
#pragma unroll
        for (int i = 0; i < 16; ++i) tot += wsum[i];
        // mean over j (1/PNUM), mean over batch (1/BATCH), avg of two preds (1/2)
        out[0] = tot * (1.0f / (2.0f * BATCH * PNUM));
    }
}

extern "C" void kernel_launch(void* const* d_in, const int* in_sizes, int n_in,
                              void* d_out, int out_size, void* d_ws, size_t ws_size,
                              hipStream_t stream) {
    const float* pred0 = (const float*)d_in[0];
    const float* pred1 = (const float*)d_in[1];
    const float* gt    = (const float*)d_in[2];
    float* out = (float*)d_out;
    float* ws  = (float*)d_ws;   // NPAIR floats = 64 KiB

    match_stage1<<<GRID1, 64 * WPB, 0, stream>>>(pred0, pred1, gt, ws);
    match_stage2<<<1, 1024, 0, stream>>>(ws, out);
}